// Round 10
// baseline (734.018 us; speedup 1.0000x reference)
//
#include <hip/hip_runtime.h>
#include <hip/hip_bf16.h>

#define NE   8
#define DIN  2048
#define DOUT 8192
#define NTOK 8192

typedef __bf16 bf16;
typedef __attribute__((ext_vector_type(8))) __bf16 bf16x8;
typedef __attribute__((ext_vector_type(16))) float f32x16;

// round-to-nearest-even f32 -> bf16 (finite inputs)
__device__ __forceinline__ bf16 f2bf(float x) {
  union { float f; unsigned u; } v; v.f = x;
  unsigned r = v.u + 0x7fffu + ((v.u >> 16) & 1u);
  union { unsigned short s; bf16 b; } o; o.s = (unsigned short)(r >> 16);
  return o.b;
}

__device__ __forceinline__ int find_expert(const void* esv, int mrow) {
  const int* p32 = (const int*)esv;
  const long long* p64 = (const long long*)esv;
  bool is64 = (p32[1] == 0);
  long long cum = 0; int e = 0;
  #pragma unroll
  for (int i = 0; i < NE; ++i) {
    long long s = is64 ? p64[i] : (long long)p32[i];
    long long nx = cum + s;
    if ((long long)mrow >= nx) e = i + 1;
    cum = nx;
  }
  return e;
}

// ---------------- pass 1a: A fp32 -> bf16 (same layout) ----------------
__global__ __launch_bounds__(256) void convertA(const float* __restrict__ A,
                                                bf16* __restrict__ Ab) {
  size_t i = ((size_t)blockIdx.x * 256 + threadIdx.x) * 8;
  float4 a = *(const float4*)(A + i);
  float4 b = *(const float4*)(A + i + 4);
  const float* f = (const float*)&a;
  const float* g = (const float*)&b;
  bf16x8 v;
  #pragma unroll
  for (int j = 0; j < 4; ++j) { v[j] = f2bf(f[j]); v[4 + j] = f2bf(g[j]); }
  *(bf16x8*)(Ab + i) = v;
}

// ------- pass 1b: W [E][K][N] fp32 -> BT [E][N][K] bf16 (transpose) -------
__global__ __launch_bounds__(256) void convertB(const float* __restrict__ W,
                                                bf16* __restrict__ BT) {
  __shared__ bf16 tile[64][66];
  const int e  = blockIdx.z;
  const int n0 = blockIdx.x * 64;
  const int k0 = blockIdx.y * 64;
  const int t  = threadIdx.x;
  const int tr = t >> 2;
  const int tc = (t & 3) << 4;

  const float* src = W + ((size_t)e * DIN + k0 + tr) * DOUT + n0 + tc;
  #pragma unroll
  for (int i = 0; i < 4; ++i) {
    float4 v = *(const float4*)(src + 4 * i);
    const float* f = (const float*)&v;
    #pragma unroll
    for (int j = 0; j < 4; ++j) tile[tr][tc + 4 * i + j] = f2bf(f[j]);
  }
  __syncthreads();

  bf16x8 v0, v1;
  #pragma unroll
  for (int j = 0; j < 8; ++j) { v0[j] = tile[tc + j][tr]; v1[j] = tile[tc + 8 + j][tr]; }
  bf16* dst = BT + ((size_t)e * DOUT + n0 + tr) * DIN + k0 + tc;
  *(bf16x8*)dst = v0;
  *(bf16x8*)(dst + 8) = v1;
}

// -- pass 2: grouped GEMM, 32x32x16 MFMA, A via LDS, B DIRECT-TO-REGISTER --
// C[m][n] = sum_k A[m][k] * BT[e][n][k]. 128x128 tile, BK=64, 4 waves (2x2).
// A-path: gload_lds + XOR swizzle (r5/r6-verified). B-path: each wave loads
// its own fragments global->VGPR (BT slice is L2-resident per r6's XCD
// order; lanes l and l+32 of one read cover complementary 16B halves of the
// same row, so lines are fully consumed within two ks-steps). This halves
// LDS staging traffic (16 KB/K-tile) and removes B ds_reads; B-load latency
// drains into the same __syncthreads that waits on A's gload_lds.
#define BM 128
#define BN 128
#define BK 64

#define GL(gp, lp) __builtin_amdgcn_global_load_lds(                        \
    (const __attribute__((address_space(1))) void*)(gp),                    \
    (__attribute__((address_space(3))) void*)(lp), 16, 0, 0)

__global__ __launch_bounds__(256, 2) void grouped_gemm(
    const bf16* __restrict__ A, const bf16* __restrict__ BT,
    const void* __restrict__ es, float* __restrict__ C) {
  __shared__ bf16 As[BM * BK];   // 16 KiB

  // XCD ntile-slice dispatch: c = XCD, ntile = c*8 + (local&7), mtile = local>>3
  const int bid   = blockIdx.x;
  const int c     = bid & 7;
  const int local = bid >> 3;            // 0..511
  const int mtile = local >> 3;          // 0..63  (ntile-fastest: share A-panel)
  const int ntile = c * 8 + (local & 7); // 0..63
  const int mrow  = mtile * BM;
  const int ncol  = ntile * BN;
  const int e     = find_expert(es, mrow);

  const int t    = threadIdx.x;
  const int lane = t & 63;
  const int w    = t >> 6;
  const int wr   = (w >> 1) * 64;          // wave rows: 0/64
  const int wc   = (w & 1) * 64;           // wave cols: 0/64
  const int l31  = lane & 31;
  const int l7   = lane & 7;
  const int kgrp = lane >> 5;              // 0/1

  // A staging: linear LDS dest (t*16B), pre-swizzled global source col
  const int srow = t >> 3;                              // 0..31
  const int ssrc = ((t & 7) ^ (srow & 7)) * 8;          // elems
  const int sdst = t * 8;                               // elems per 32-row chunk
  const bf16* Ag = A + (size_t)(mrow + srow) * DIN + ssrc;

  // B direct: wave's fragment rows (fn = 0/1), per-lane k-granule
  const bf16* Bw = BT + ((size_t)e * DOUT + ncol + wc + l31) * DIN;
  const int bko = kgrp * 8;   // elems within a 16-elem granule pair

  f32x16 acc[2][2];
  #pragma unroll
  for (int fm = 0; fm < 2; ++fm)
    #pragma unroll
    for (int fn = 0; fn < 2; ++fn)
      #pragma unroll
      for (int r = 0; r < 16; ++r) acc[fm][fn][r] = 0.f;

  for (int kt = 0; kt < DIN / BK; ++kt) {
    const int kb = kt * BK;

    // A stage via global_load_lds (swizzled source)
    #pragma unroll
    for (int i = 0; i < 4; ++i)
      GL(Ag + (size_t)(i * 32) * DIN + kb, As + i * 2048 + sdst);

    // B fragments: global -> VGPR (8 x dwordx4 per wave)
    bf16x8 bF[2][4];
    #pragma unroll
    for (int fn = 0; fn < 2; ++fn)
      #pragma unroll
      for (int ks = 0; ks < 4; ++ks)
        bF[fn][ks] = *(const bf16x8*)&Bw[(size_t)(fn * 32) * DIN + kb + ks * 16 + bko];

    __syncthreads();   // drains vmcnt: A staged AND B regs ready

    #pragma unroll
    for (int ks = 0; ks < 4; ++ks) {
      const int g = ((ks * 2 + kgrp) ^ l7) * 8;   // swizzled granule (elems)
      bf16x8 aF[2];
      #pragma unroll
      for (int fm = 0; fm < 2; ++fm)
        aF[fm] = *(const bf16x8*)&As[(wr + fm * 32 + l31) * BK + g];
      #pragma unroll
      for (int fm = 0; fm < 2; ++fm)
        #pragma unroll
        for (int fn = 0; fn < 2; ++fn)
          acc[fm][fn] = __builtin_amdgcn_mfma_f32_32x32x16_bf16(
              aF[fm], bF[fn][ks], acc[fm][fn], 0, 0, 0);
    }
    __syncthreads();
  }

  // C/D layout: col = lane&31, row = (reg&3) + 8*(reg>>2) + 4*(lane>>5)
  float* Cb = C + (size_t)mrow * DOUT + ncol;
  #pragma unroll
  for (int fm = 0; fm < 2; ++fm)
    #pragma unroll
    for (int fn = 0; fn < 2; ++fn)
      #pragma unroll
      for (int r = 0; r < 16; ++r) {
        const int row = wr + fm * 32 + (r & 3) + 8 * (r >> 2) + 4 * kgrp;
        const int col = wc + fn * 32 + l31;
        Cb[(size_t)row * DOUT + col] = acc[fm][fn][r];
      }
}

// ---------------- fallback (ws too small): fp32 tiled GEMM ----------------
__global__ __launch_bounds__(256) void fallback_gemm(
    const float* __restrict__ A, const float* __restrict__ W,
    const void* __restrict__ es, float* __restrict__ C) {
  __shared__ float Asf[64][17];
  __shared__ float Bsf[16][65];
  const int bid = blockIdx.x;
  const int mtile = bid >> 7;
  const int ntile = bid & 127;
  const int mrow = mtile * 64, ncol = ntile * 64;
  const int e = find_expert(es, mrow);
  const int t = threadIdx.x;
  const int tx = t & 15, ty = t >> 4;
  float acc[4][4] = {};
  const float* Ab = A + (size_t)mrow * DIN;
  const float* Wb = W + (size_t)e * DIN * DOUT + ncol;
  for (int kb = 0; kb < DIN; kb += 16) {
    {
      const int r = t >> 2, cc = (t & 3) * 4;
      float4 v = *(const float4*)(Ab + (size_t)r * DIN + kb + cc);
      const float* f = (const float*)&v;
      #pragma unroll
      for (int j = 0; j < 4; ++j) Asf[r][cc + j] = f[j];
      const int r2 = t >> 4, c2 = (t & 15) * 4;
      float4 wv = *(const float4*)(Wb + (size_t)(kb + r2) * DOUT + c2);
      const float* g = (const float*)&wv;
      #pragma unroll
      for (int j = 0; j < 4; ++j) Bsf[r2][c2 + j] = g[j];
    }
    __syncthreads();
    #pragma unroll
    for (int k = 0; k < 16; ++k)
      #pragma unroll
      for (int i = 0; i < 4; ++i)
        #pragma unroll
        for (int j = 0; j < 4; ++j)
          acc[i][j] += Asf[ty * 4 + i][k] * Bsf[k][tx * 4 + j];
    __syncthreads();
  }
  #pragma unroll
  for (int i = 0; i < 4; ++i)
    #pragma unroll
    for (int j = 0; j < 4; ++j)
      C[(size_t)(mrow + ty * 4 + i) * DOUT + ncol + tx * 4 + j] = acc[i][j];
}

extern "C" void kernel_launch(void* const* d_in, const int* in_sizes, int n_in,
                              void* d_out, int out_size, void* d_ws, size_t ws_size,
                              hipStream_t stream) {
  const float* A = (const float*)d_in[0];
  const float* W = (const float*)d_in[1];
  const void*  es = (const void*)d_in[2];
  float* C = (float*)d_out;

  const size_t needA = (size_t)NTOK * DIN * sizeof(bf16);        // 32 MB
  const size_t needB = (size_t)NE * DIN * DOUT * sizeof(bf16);   // 256 MB

  if (ws_size >= needA + needB) {
    bf16* Ab = (bf16*)d_ws;
    bf16* BT = (bf16*)((char*)d_ws + needA);
    convertA<<<(NTOK * DIN) / (256 * 8), 256, 0, stream>>>(A, Ab);
    dim3 gB(DOUT / 64, DIN / 64, NE);
    convertB<<<gB, 256, 0, stream>>>(W, BT);
    grouped_gemm<<<(NTOK / BM) * (DOUT / BN), 256, 0, stream>>>(Ab, BT, es, C);
  } else {
    fallback_gemm<<<(NTOK / 64) * (DOUT / 64), 256, 0, stream>>>(A, W, es, C);
  }
}

// Round 12
// 526.758 us; speedup vs baseline: 1.3935x; 1.3935x over previous
//
#include <hip/hip_runtime.h>
#include <hip/hip_bf16.h>

#define NE   8
#define DIN  2048
#define DOUT 8192
#define NTOK 8192

typedef __bf16 bf16;
typedef __attribute__((ext_vector_type(8))) __bf16 bf16x8;
typedef __attribute__((ext_vector_type(16))) float f32x16;

// round-to-nearest-even f32 -> bf16 (finite inputs)
__device__ __forceinline__ bf16 f2bf(float x) {
  union { float f; unsigned u; } v; v.f = x;
  unsigned r = v.u + 0x7fffu + ((v.u >> 16) & 1u);
  union { unsigned short s; bf16 b; } o; o.s = (unsigned short)(r >> 16);
  return o.b;
}

__device__ __forceinline__ int find_expert(const void* esv, int mrow) {
  const int* p32 = (const int*)esv;
  const long long* p64 = (const long long*)esv;
  bool is64 = (p32[1] == 0);
  long long cum = 0; int e = 0;
  #pragma unroll
  for (int i = 0; i < NE; ++i) {
    long long s = is64 ? p64[i] : (long long)p32[i];
    long long nx = cum + s;
    if ((long long)mrow >= nx) e = i + 1;
    cum = nx;
  }
  return e;
}

// ---------------- pass 1a: A fp32 -> bf16 (same layout) ----------------
__global__ __launch_bounds__(256) void convertA(const float* __restrict__ A,
                                                bf16* __restrict__ Ab) {
  size_t i = ((size_t)blockIdx.x * 256 + threadIdx.x) * 8;
  float4 a = *(const float4*)(A + i);
  float4 b = *(const float4*)(A + i + 4);
  const float* f = (const float*)&a;
  const float* g = (const float*)&b;
  bf16x8 v;
  #pragma unroll
  for (int j = 0; j < 4; ++j) { v[j] = f2bf(f[j]); v[4 + j] = f2bf(g[j]); }
  *(bf16x8*)(Ab + i) = v;
}

// ------- pass 1b: W [E][K][N] fp32 -> BT [E][N][K] bf16 (transpose) -------
__global__ __launch_bounds__(256) void convertB(const float* __restrict__ W,
                                                bf16* __restrict__ BT) {
  __shared__ bf16 tile[64][66];
  const int e  = blockIdx.z;
  const int n0 = blockIdx.x * 64;
  const int k0 = blockIdx.y * 64;
  const int t  = threadIdx.x;
  const int tr = t >> 2;
  const int tc = (t & 3) << 4;

  const float* src = W + ((size_t)e * DIN + k0 + tr) * DOUT + n0 + tc;
  #pragma unroll
  for (int i = 0; i < 4; ++i) {
    float4 v = *(const float4*)(src + 4 * i);
    const float* f = (const float*)&v;
    #pragma unroll
    for (int j = 0; j < 4; ++j) tile[tr][tc + 4 * i + j] = f2bf(f[j]);
  }
  __syncthreads();

  bf16x8 v0, v1;
  #pragma unroll
  for (int j = 0; j < 8; ++j) { v0[j] = tile[tc + j][tr]; v1[j] = tile[tc + 8 + j][tr]; }
  bf16* dst = BT + ((size_t)e * DOUT + n0 + tr) * DIN + k0 + tc;
  *(bf16x8*)dst = v0;
  *(bf16x8*)(dst + 8) = v1;
}

// ---- pass 2: grouped GEMM, 32x32x16 MFMA, BK=32 high-TLP m97 structure ----
// C[m][n] = sum_k A[m][k] * BT[e][n][k]. 128x128 tile, 4 waves (2x2),
// 16 KiB LDS -> high blocks/CU co-residency; cross-block overlap (m114)
// hides the per-K-tile barrier drain. Swizzle for 64B rows (BK=32), SAME
// involution f(row) = (row>>1)&3 on BOTH sides (r11 bug: staging used
// row&3 -> mismatch -> wrong data): staging source col ((t&3)^((t>>3)&3)),
// read granule (ks*2+kgrp) ^ ((l31>>1)&3). Bank math: 16-lane quarter ->
// 8 (parity,slot) groups x 2 lanes = 2-way = free (m136).
// L2-coop XCD order (r6-verified): XCD c owns ntiles [8c,8c+8).
#define BM 128
#define BN 128
#define BK 32

#define GL(gp, lp) __builtin_amdgcn_global_load_lds(                        \
    (const __attribute__((address_space(1))) void*)(gp),                    \
    (__attribute__((address_space(3))) void*)(lp), 16, 0, 0)

__global__ __launch_bounds__(256, 4) void grouped_gemm(
    const bf16* __restrict__ A, const bf16* __restrict__ BT,
    const void* __restrict__ es, float* __restrict__ C) {
  __shared__ bf16 As[BM * BK];   // 8 KiB
  __shared__ bf16 Bs[BN * BK];   // 8 KiB

  // XCD ntile-slice dispatch: c = XCD, ntile = c*8 + (local&7), mtile = local>>3
  const int bid   = blockIdx.x;
  const int c     = bid & 7;
  const int local = bid >> 3;            // 0..511
  const int mtile = local >> 3;          // 0..63  (ntile-fastest: share A-panel)
  const int ntile = c * 8 + (local & 7); // 0..63
  const int mrow  = mtile * BM;
  const int ncol  = ntile * BN;
  const int e     = find_expert(es, mrow);

  const int t    = threadIdx.x;
  const int lane = t & 63;
  const int w    = t >> 6;
  const int wr   = (w >> 1) * 64;          // wave rows: 0/64
  const int wc   = (w & 1) * 64;           // wave cols: 0/64
  const int l31  = lane & 31;
  const int kgrp = lane >> 5;              // 0/1

  // staging: linear LDS dest (t*16B), pre-swizzled global source col.
  // thread t covers row srow = t>>2 (and srow+64), granule t&3.
  // f(row) = (row>>1)&3 -> source col ((t&3) ^ ((t>>3)&3)) * 8.
  const int srow = t >> 2;                              // 0..63
  const int ssrc = ((t & 3) ^ ((t >> 3) & 3)) * 8;      // elems
  const int sdst = t * 8;                               // elems per 64-row chunk

  const bf16* Ag = A + (size_t)(mrow + srow) * DIN + ssrc;
  const bf16* Bg = BT + ((size_t)e * DOUT + ncol + srow) * DIN + ssrc;

  f32x16 acc[2][2];
  #pragma unroll
  for (int fm = 0; fm < 2; ++fm)
    #pragma unroll
    for (int fn = 0; fn < 2; ++fn)
      #pragma unroll
      for (int r = 0; r < 16; ++r) acc[fm][fn][r] = 0.f;

  for (int kt = 0; kt < DIN / BK; ++kt) {
    const int kb = kt * BK;
    #pragma unroll
    for (int i = 0; i < 2; ++i) {
      GL(Ag + (size_t)(i * 64) * DIN + kb, As + i * 2048 + sdst);
      GL(Bg + (size_t)(i * 64) * DIN + kb, Bs + i * 2048 + sdst);
    }
    __syncthreads();   // compiler drains vmcnt before s_barrier

    #pragma unroll
    for (int ks = 0; ks < 2; ++ks) {
      const int g = ((ks * 2 + kgrp) ^ ((l31 >> 1) & 3)) * 8;   // swizzled (elems)
      bf16x8 aF[2], bF[2];
      #pragma unroll
      for (int fm = 0; fm < 2; ++fm)
        aF[fm] = *(const bf16x8*)&As[(wr + fm * 32 + l31) * BK + g];
      #pragma unroll
      for (int fn = 0; fn < 2; ++fn)
        bF[fn] = *(const bf16x8*)&Bs[(wc + fn * 32 + l31) * BK + g];
      #pragma unroll
      for (int fm = 0; fm < 2; ++fm)
        #pragma unroll
        for (int fn = 0; fn < 2; ++fn)
          acc[fm][fn] = __builtin_amdgcn_mfma_f32_32x32x16_bf16(
              aF[fm], bF[fn], acc[fm][fn], 0, 0, 0);
    }
    __syncthreads();
  }

  // C/D layout: col = lane&31, row = (reg&3) + 8*(reg>>2) + 4*(lane>>5)
  float* Cb = C + (size_t)mrow * DOUT + ncol;
  #pragma unroll
  for (int fm = 0; fm < 2; ++fm)
    #pragma unroll
    for (int fn = 0; fn < 2; ++fn)
      #pragma unroll
      for (int r = 0; r < 16; ++r) {
        const int row = wr + fm * 32 + (r & 3) + 8 * (r >> 2) + 4 * kgrp;
        const int col = wc + fn * 32 + l31;
        Cb[(size_t)row * DOUT + col] = acc[fm][fn][r];
      }
}

// ---------------- fallback (ws too small): fp32 tiled GEMM ----------------
__global__ __launch_bounds__(256) void fallback_gemm(
    const float* __restrict__ A, const float* __restrict__ W,
    const void* __restrict__ es, float* __restrict__ C) {
  __shared__ float Asf[64][17];
  __shared__ float Bsf[16][65];
  const int bid = blockIdx.x;
  const int mtile = bid >> 7;
  const int ntile = bid & 127;
  const int mrow = mtile * 64, ncol = ntile * 64;
  const int e = find_expert(es, mrow);
  const int t = threadIdx.x;
  const int tx = t & 15, ty = t >> 4;
  float acc[4][4] = {};
  const float* Ab = A + (size_t)mrow * DIN;
  const float* Wb = W + (size_t)e * DIN * DOUT + ncol;
  for (int kb = 0; kb < DIN; kb += 16) {
    {
      const int r = t >> 2, cc = (t & 3) * 4;
      float4 v = *(const float4*)(Ab + (size_t)r * DIN + kb + cc);
      const float* f = (const float*)&v;
      #pragma unroll
      for (int j = 0; j < 4; ++j) Asf[r][cc + j] = f[j];
      const int r2 = t >> 4, c2 = (t & 15) * 4;
      float4 wv = *(const float4*)(Wb + (size_t)(kb + r2) * DOUT + c2);
      const float* g = (const float*)&wv;
      #pragma unroll
      for (int j = 0; j < 4; ++j) Bsf[r2][c2 + j] = g[j];
    }
    __syncthreads();
    #pragma unroll
    for (int k = 0; k < 16; ++k)
      #pragma unroll
      for (int i = 0; i < 4; ++i)
        #pragma unroll
        for (int j = 0; j < 4; ++j)
          acc[i][j] += Asf[ty * 4 + i][k] * Bsf[k][tx * 4 + j];
    __syncthreads();
  }
  #pragma unroll
  for (int i = 0; i < 4; ++i)
    #pragma unroll
    for (int j = 0; j < 4; ++j)
      C[(size_t)(mrow + ty * 4 + i) * DOUT + ncol + tx * 4 + j] = acc[i][j];
}

extern "C" void kernel_launch(void* const* d_in, const int* in_sizes, int n_in,
                              void* d_out, int out_size, void* d_ws, size_t ws_size,
                              hipStream_t stream) {
  const float* A = (const float*)d_in[0];
  const float* W = (const float*)d_in[1];
  const void*  es = (const void*)d_in[2];
  float* C = (float*)d_out;

  const size_t needA = (size_t)NTOK * DIN * sizeof(bf16);        // 32 MB
  const size_t needB = (size_t)NE * DIN * DOUT * sizeof(bf16);   // 256 MB

  if (ws_size >= needA + needB) {
    bf16* Ab = (bf16*)d_ws;
    bf16* BT = (bf16*)((char*)d_ws + needA);
    convertA<<<(NTOK * DIN) / (256 * 8), 256, 0, stream>>>(A, Ab);
    dim3 gB(DOUT / 64, DIN / 64, NE);
    convertB<<<gB, 256, 0, stream>>>(W, BT);
    grouped_gemm<<<(NTOK / BM) * (DOUT / BN), 256, 0, stream>>>(Ab, BT, es, C);
  } else {
    fallback_gemm<<<(NTOK / 64) * (DOUT / 64), 256, 0, stream>>>(A, W, es, C);
  }
}

// Round 13
// 478.305 us; speedup vs baseline: 1.5346x; 1.1013x over previous
//
#include <hip/hip_runtime.h>
#include <hip/hip_bf16.h>

#define NE   8
#define DIN  2048
#define DOUT 8192
#define NTOK 8192

typedef __bf16 bf16;
typedef __attribute__((ext_vector_type(8))) __bf16 bf16x8;
typedef __attribute__((ext_vector_type(16))) float f32x16;

// round-to-nearest-even f32 -> bf16 (finite inputs)
__device__ __forceinline__ bf16 f2bf(float x) {
  union { float f; unsigned u; } v; v.f = x;
  unsigned r = v.u + 0x7fffu + ((v.u >> 16) & 1u);
  union { unsigned short s; bf16 b; } o; o.s = (unsigned short)(r >> 16);
  return o.b;
}

__device__ __forceinline__ int find_expert(const void* esv, int mrow) {
  const int* p32 = (const int*)esv;
  const long long* p64 = (const long long*)esv;
  bool is64 = (p32[1] == 0);
  long long cum = 0; int e = 0;
  #pragma unroll
  for (int i = 0; i < NE; ++i) {
    long long s = is64 ? p64[i] : (long long)p32[i];
    long long nx = cum + s;
    if ((long long)mrow >= nx) e = i + 1;
    cum = nx;
  }
  return e;
}

// ---------------- pass 1a: A fp32 -> bf16 (same layout) ----------------
__global__ __launch_bounds__(256) void convertA(const float* __restrict__ A,
                                                bf16* __restrict__ Ab) {
  size_t i = ((size_t)blockIdx.x * 256 + threadIdx.x) * 8;
  float4 a = *(const float4*)(A + i);
  float4 b = *(const float4*)(A + i + 4);
  const float* f = (const float*)&a;
  const float* g = (const float*)&b;
  bf16x8 v;
  #pragma unroll
  for (int j = 0; j < 4; ++j) { v[j] = f2bf(f[j]); v[4 + j] = f2bf(g[j]); }
  *(bf16x8*)(Ab + i) = v;
}

// ------- pass 1b: W [E][K][N] fp32 -> BT [E][N][K] bf16 (transpose) -------
__global__ __launch_bounds__(256) void convertB(const float* __restrict__ W,
                                                bf16* __restrict__ BT) {
  __shared__ bf16 tile[64][66];
  const int e  = blockIdx.z;
  const int n0 = blockIdx.x * 64;
  const int k0 = blockIdx.y * 64;
  const int t  = threadIdx.x;
  const int tr = t >> 2;
  const int tc = (t & 3) << 4;

  const float* src = W + ((size_t)e * DIN + k0 + tr) * DOUT + n0 + tc;
  #pragma unroll
  for (int i = 0; i < 4; ++i) {
    float4 v = *(const float4*)(src + 4 * i);
    const float* f = (const float*)&v;
    #pragma unroll
    for (int j = 0; j < 4; ++j) tile[tr][tc + 4 * i + j] = f2bf(f[j]);
  }
  __syncthreads();

  bf16x8 v0, v1;
  #pragma unroll
  for (int j = 0; j < 8; ++j) { v0[j] = tile[tc + j][tr]; v1[j] = tile[tc + 8 + j][tr]; }
  bf16* dst = BT + ((size_t)e * DOUT + n0 + tr) * DIN + k0 + tc;
  *(bf16x8*)dst = v0;
  *(bf16x8*)(dst + 8) = v1;
}

// ---- pass 2: grouped GEMM, m97 structure + XOR swizzle + 32x32x16 MFMA ----
// C[m][n] = sum_k A[m][k] * BT[e][n][k]. 128x128 tile, BK=64, 4 waves (2x2),
// each wave 64x64 = 2x2 fragments of 32x32. 32 KiB LDS, multi-block/CU
// (implicit cross-block overlap hides barrier drains, m114).
// Swizzle (r5/r6-verified): granule g' = g ^ (row&7), SAME involution on
// both sides: staging = linear LDS dest + pre-swizzled global source col;
// read granule = (ks*2+kgrp) ^ (lane&7).
// L2-coop order (r6-verified): XCD c owns ntiles [8c,8c+8) x all mtiles,
// ntile-fastest -> each B-panel fetched by exactly one XCD (L2-resident),
// A streams from L3. Frag layout 32x32x16: A/B row = lane&31,
// kgrp = lane>>5; C/D col = lane&31, row = (reg&3)+8*(reg>>2)+4*(lane>>5).
#define BM 128
#define BN 128
#define BK 64

#define GL(gp, lp) __builtin_amdgcn_global_load_lds(                        \
    (const __attribute__((address_space(1))) void*)(gp),                    \
    (__attribute__((address_space(3))) void*)(lp), 16, 0, 0)

__global__ __launch_bounds__(256) void grouped_gemm(
    const bf16* __restrict__ A, const bf16* __restrict__ BT,
    const void* __restrict__ es, float* __restrict__ C) {
  __shared__ bf16 As[BM * BK];
  __shared__ bf16 Bs[BN * BK];

  // XCD ntile-slice dispatch: c = XCD, ntile = c*8 + (local&7), mtile = local>>3
  const int bid   = blockIdx.x;
  const int c     = bid & 7;
  const int local = bid >> 3;            // 0..511
  const int mtile = local >> 3;          // 0..63  (ntile-fastest: share A-panel)
  const int ntile = c * 8 + (local & 7); // 0..63
  const int mrow  = mtile * BM;
  const int ncol  = ntile * BN;
  const int e     = find_expert(es, mrow);

  const int t    = threadIdx.x;
  const int lane = t & 63;
  const int w    = t >> 6;
  const int wr   = (w >> 1) * 64;          // wave rows: 0/64
  const int wc   = (w & 1) * 64;           // wave cols: 0/64
  const int l31  = lane & 31;
  const int l7   = lane & 7;
  const int kgrp = lane >> 5;              // 0/1

  // staging: linear LDS dest (t*16B), pre-swizzled global source col
  const int srow = t >> 3;                              // 0..31
  const int ssrc = ((t & 7) ^ (srow & 7)) * 8;          // elems
  const int sdst = t * 8;                               // elems per 32-row chunk

  const bf16* Ag = A + (size_t)(mrow + srow) * DIN + ssrc;
  const bf16* Bg = BT + ((size_t)e * DOUT + ncol + srow) * DIN + ssrc;

  f32x16 acc[2][2];
  #pragma unroll
  for (int fm = 0; fm < 2; ++fm)
    #pragma unroll
    for (int fn = 0; fn < 2; ++fn)
      #pragma unroll
      for (int r = 0; r < 16; ++r) acc[fm][fn][r] = 0.f;

  for (int kt = 0; kt < DIN / BK; ++kt) {
    const int kb = kt * BK;
    #pragma unroll
    for (int i = 0; i < 4; ++i) {
      GL(Ag + (size_t)(i * 32) * DIN + kb, As + i * 2048 + sdst);
      GL(Bg + (size_t)(i * 32) * DIN + kb, Bs + i * 2048 + sdst);
    }
    __syncthreads();   // compiler drains vmcnt before s_barrier

    #pragma unroll
    for (int ks = 0; ks < 4; ++ks) {
      const int g = ((ks * 2 + kgrp) ^ l7) * 8;   // swizzled granule (elems)
      bf16x8 aF[2], bF[2];
      #pragma unroll
      for (int fm = 0; fm < 2; ++fm)
        aF[fm] = *(const bf16x8*)&As[(wr + fm * 32 + l31) * BK + g];
      #pragma unroll
      for (int fn = 0; fn < 2; ++fn)
        bF[fn] = *(const bf16x8*)&Bs[(wc + fn * 32 + l31) * BK + g];
      #pragma unroll
      for (int fm = 0; fm < 2; ++fm)
        #pragma unroll
        for (int fn = 0; fn < 2; ++fn)
          acc[fm][fn] = __builtin_amdgcn_mfma_f32_32x32x16_bf16(
              aF[fm], bF[fn], acc[fm][fn], 0, 0, 0);
    }
    __syncthreads();
  }

  // C/D layout: col = lane&31, row = (reg&3) + 8*(reg>>2) + 4*(lane>>5)
  float* Cb = C + (size_t)mrow * DOUT + ncol;
  #pragma unroll
  for (int fm = 0; fm < 2; ++fm)
    #pragma unroll
    for (int fn = 0; fn < 2; ++fn)
      #pragma unroll
      for (int r = 0; r < 16; ++r) {
        const int row = wr + fm * 32 + (r & 3) + 8 * (r >> 2) + 4 * kgrp;
        const int col = wc + fn * 32 + l31;
        Cb[(size_t)row * DOUT + col] = acc[fm][fn][r];
      }
}

// ---------------- fallback (ws too small): fp32 tiled GEMM ----------------
__global__ __launch_bounds__(256) void fallback_gemm(
    const float* __restrict__ A, const float* __restrict__ W,
    const void* __restrict__ es, float* __restrict__ C) {
  __shared__ float Asf[64][17];
  __shared__ float Bsf[16][65];
  const int bid = blockIdx.x;
  const int mtile = bid >> 7;
  const int ntile = bid & 127;
  const int mrow = mtile * 64, ncol = ntile * 64;
  const int e = find_expert(es, mrow);
  const int t = threadIdx.x;
  const int tx = t & 15, ty = t >> 4;
  float acc[4][4] = {};
  const float* Ab = A + (size_t)mrow * DIN;
  const float* Wb = W + (size_t)e * DIN * DOUT + ncol;
  for (int kb = 0; kb < DIN; kb += 16) {
    {
      const int r = t >> 2, cc = (t & 3) * 4;
      float4 v = *(const float4*)(Ab + (size_t)r * DIN + kb + cc);
      const float* f = (const float*)&v;
      #pragma unroll
      for (int j = 0; j < 4; ++j) Asf[r][cc + j] = f[j];
      const int r2 = t >> 4, c2 = (t & 15) * 4;
      float4 wv = *(const float4*)(Wb + (size_t)(kb + r2) * DOUT + c2);
      const float* g = (const float*)&wv;
      #pragma unroll
      for (int j = 0; j < 4; ++j) Bsf[r2][c2 + j] = g[j];
    }
    __syncthreads();
    #pragma unroll
    for (int k = 0; k < 16; ++k)
      #pragma unroll
      for (int i = 0; i < 4; ++i)
        #pragma unroll
        for (int j = 0; j < 4; ++j)
          acc[i][j] += Asf[ty * 4 + i][k] * Bsf[k][tx * 4 + j];
    __syncthreads();
  }
  #pragma unroll
  for (int i = 0; i < 4; ++i)
    #pragma unroll
    for (int j = 0; j < 4; ++j)
      C[(size_t)(mrow + ty * 4 + i) * DOUT + ncol + tx * 4 + j] = acc[i][j];
}

extern "C" void kernel_launch(void* const* d_in, const int* in_sizes, int n_in,
                              void* d_out, int out_size, void* d_ws, size_t ws_size,
                              hipStream_t stream) {
  const float* A = (const float*)d_in[0];
  const float* W = (const float*)d_in[1];
  const void*  es = (const void*)d_in[2];
  float* C = (float*)d_out;

  const size_t needA = (size_t)NTOK * DIN * sizeof(bf16);        // 32 MB
  const size_t needB = (size_t)NE * DIN * DOUT * sizeof(bf16);   // 256 MB

  if (ws_size >= needA + needB) {
    bf16* Ab = (bf16*)d_ws;
    bf16* BT = (bf16*)((char*)d_ws + needA);
    convertA<<<(NTOK * DIN) / (256 * 8), 256, 0, stream>>>(A, Ab);
    dim3 gB(DOUT / 64, DIN / 64, NE);
    convertB<<<gB, 256, 0, stream>>>(W, BT);
    grouped_gemm<<<(NTOK / BM) * (DOUT / BN), 256, 0, stream>>>(Ab, BT, es, C);
  } else {
    fallback_gemm<<<(NTOK / 64) * (DOUT / 64), 256, 0, stream>>>(A, W, es, C);
  }
}